// Round 22
// baseline (3130.553 us; speedup 1.0000x reference)
//
#include <hip/hip_runtime.h>

#define Bb 256
#define Ll 1024
#define CH 16

typedef _Float16 h2v __attribute__((ext_vector_type(2)));

__device__ __forceinline__ unsigned pack_h2(float a, float b) {
  h2v v; v[0] = (_Float16)a; v[1] = (_Float16)b;
  return __builtin_bit_cast(unsigned, v);
}
__device__ __forceinline__ float dot2(unsigned w, unsigned x, float acc) {
#if defined(__has_builtin) && __has_builtin(__builtin_amdgcn_fdot2)
  return __builtin_amdgcn_fdot2(__builtin_bit_cast(h2v, w),
                                __builtin_bit_cast(h2v, x), acc, false);
#else
  h2v wv = __builtin_bit_cast(h2v, w), xv = __builtin_bit_cast(h2v, x);
  acc = fmaf((float)wv[0], (float)xv[0], acc);
  return fmaf((float)wv[1], (float)xv[1], acc);
#endif
}
__device__ __forceinline__ float dppadd1(float v) {   // + lane^1
  int s = __builtin_amdgcn_mov_dpp(__builtin_bit_cast(int, v), 0xB1, 0xF, 0xF, true);
  return v + __builtin_bit_cast(float, s);
}
__device__ __forceinline__ float dppadd2(float v) {   // + lane^2
  int s = __builtin_amdgcn_mov_dpp(__builtin_bit_cast(int, v), 0x4E, 0xF, 0xF, true);
  return v + __builtin_bit_cast(float, s);
}
__device__ __forceinline__ float qsum(float a0, float a1) {
  return dppadd2(dppadd1(a0 + a1));   // quad-uniform sum
}
__device__ __forceinline__ float fast_tanh(float x) {
  float e = __expf(2.0f * x);
  return 1.0f - 2.0f / (e + 1.0f);
}
__device__ __forceinline__ float fast_sigmoid(float x) {
  return 1.0f / (1.0f + __expf(-x));
}

// 32-wide K-slice matvec (r12/r19-verified)
__device__ __forceinline__ float mv16(const unsigned* __restrict__ w,
                                      const unsigned* __restrict__ v, int q0) {
  float a0 = 0.0f, a1 = 0.0f;
#pragma unroll
  for (int c = 0; c < 4; ++c) {
    const uint4 hv = *(const uint4*)&v[q0 + 4 * c];
    a0 = dot2(w[4*c+0], hv.x, a0); a1 = dot2(w[4*c+1], hv.y, a1);
    a0 = dot2(w[4*c+2], hv.z, a0); a1 = dot2(w[4*c+3], hv.w, a1);
  }
  return qsum(a0, a1);
}
// dual matvec sharing the B-vector loads
__device__ __forceinline__ void mv16x2(const unsigned* __restrict__ wA,
                                       const unsigned* __restrict__ wB,
                                       const unsigned* __restrict__ v, int q0,
                                       float& rA, float& rB) {
  float a0 = 0.f, a1 = 0.f, c0 = 0.f, c1 = 0.f;
#pragma unroll
  for (int c = 0; c < 4; ++c) {
    const uint4 hv = *(const uint4*)&v[q0 + 4 * c];
    a0 = dot2(wA[4*c+0], hv.x, a0); a1 = dot2(wA[4*c+1], hv.y, a1);
    a0 = dot2(wA[4*c+2], hv.z, a0); a1 = dot2(wA[4*c+3], hv.w, a1);
    c0 = dot2(wB[4*c+0], hv.x, c0); c1 = dot2(wB[4*c+1], hv.y, c1);
    c0 = dot2(wB[4*c+2], hv.z, c0); c1 = dot2(wB[4*c+3], hv.w, c1);
  }
  rA = qsum(a0, a1); rB = qsum(c0, c1);
}

// ---- prepass into ws (66048 words = 258 KB, r17-proven size) ----
// f32: [0,16384) M=W1·W2 ; [16384,16512) c=W1·b2 ; [16512,16896) d=Whh·b2
// u32: [16896,41472) N16 = f16-pair(Whh·W2, 384x128) ; [41472,66048) Wih16
__global__ __launch_bounds__(256) void k_prep(
    const float* __restrict__ W1, const float* __restrict__ W2,
    const float* __restrict__ Whh, const float* __restrict__ Wih,
    const float* __restrict__ b2, float* __restrict__ ws)
{
  unsigned* wsu = (unsigned*)ws;
  const int idx = blockIdx.x * 256 + threadIdx.x;
  if (idx < 16384) {
    const int i = idx >> 7, j = idx & 127;
    float s = 0.f;
    for (int k = 0; k < 128; ++k) s = fmaf(W1[i * 128 + k], W2[k * 128 + j], s);
    ws[idx] = s;
  } else if (idx < 16512) {
    const int i = idx - 16384;
    float s = 0.f;
    for (int k = 0; k < 128; ++k) s = fmaf(W1[i * 128 + k], b2[k], s);
    ws[idx] = s;
  } else if (idx < 16896) {
    const int r = idx - 16512;
    float s = 0.f;
    for (int k = 0; k < 128; ++k) s = fmaf(Whh[r * 128 + k], b2[k], s);
    ws[idx] = s;
  } else if (idx < 41472) {
    const int e = idx - 16896;
    const int r = e >> 6, w = e & 63;
    float s0 = 0.f, s1 = 0.f;
    for (int k = 0; k < 128; ++k) {
      const float wh = Whh[r * 128 + k];
      s0 = fmaf(wh, W2[k * 128 + 2 * w], s0);
      s1 = fmaf(wh, W2[k * 128 + 2 * w + 1], s1);
    }
    wsu[idx] = pack_h2(s0, s1);
  } else if (idx < 66048) {
    const int e = idx - 41472;
    const int r = e >> 6, w = e & 63;
    wsu[idx] = pack_h2(Wih[r * 128 + 2 * w], Wih[r * 128 + 2 * w + 1]);
  }
}

// One WG (512 thr) per batch row. 5 phases/step:
// P1: v=W1·h0, Whh_r·h0 | P2: v+=sv(M·u0+c), Whh_z·h0 | P3: ..., Whh_n·h0
// P4: v+=sv(M·u2+c), usum | P5: {W2,N_r,N_z,N_n}·usum + gates in-register.
// gi/xe computed per-16-step chunk (Wih streamed from L2, one gate at a time).
__global__ __launch_bounds__(512, 1) void k_fused(
    const float* __restrict__ x, const float* __restrict__ dtp,
    const int* __restrict__ mask,
    const float* __restrict__ Wx, const float* __restrict__ bx,
    const float* __restrict__ W1, const float* __restrict__ b1,
    const float* __restrict__ W2, const float* __restrict__ b2,
    const float* __restrict__ Wih, const float* __restrict__ bih,
    const float* __restrict__ Whh, const float* __restrict__ bhh,
    const float* __restrict__ lng, const float* __restrict__ lnb,
    const float* __restrict__ Whd, const float* __restrict__ bhp,
    const float* __restrict__ ws,
    float* __restrict__ out)
{
  const float* Mf = ws;
  const float* cf = ws + 16384;
  const float* df = ws + 16512;
  const unsigned* wsu = (const unsigned*)ws;
  const unsigned* N16 = wsu + 16896;
  const unsigned* W16 = wsu + 41472;

  const int b = blockIdx.x;
  const int tid = threadIdx.x;
  const int lane = tid & 63;
  const int wv = tid >> 6;
  const int jl = lane >> 2;
  const int ks = lane & 3;
  const int j = (wv << 4) + jl;
  const int q0 = ks << 4;
  const int q0x = ks << 3;
  const int swi = (j & 15) << 2;

  __shared__ unsigned actb[32];                             // bitpacked
  __shared__ __align__(16) unsigned n_lds[384 * 64];        // 96 KB, swizzled
  __shared__ __align__(16) unsigned w2_lds[128 * 64];       // 32 KB, swizzled
  __shared__ __align__(16) unsigned x16[2][CH * 32];        // 4 KB
  __shared__ __align__(16) unsigned xech[CH * 64];          // 4 KB (chunk xe)
  __shared__ _Float16 gich[3 * CH * 128];                   // 12 KB (chunk gi)
  __shared__ __align__(16) unsigned ubuf[2][64];
  __shared__ __align__(16) unsigned usumb[64];
  __shared__ __align__(16) unsigned h16[2][64];
  __shared__ float dt_ch[2][CH];
  __shared__ int   m_ch[2][CH];
  __shared__ float red_lds[48];
  __shared__ float cc_lds[2];

  if (tid < 32) actb[tid] = 0u;
  __syncthreads();
  for (int t0 = tid; t0 < Ll; t0 += 512) {
    int a = 0;
#pragma unroll 8
    for (int bb = 0; bb < Bb; ++bb) a |= mask[(size_t)bb * Ll + t0];
    if (a) atomicOr(&actb[t0 >> 5], 1u << (t0 & 31));
  }
  // ---- N -> LDS (XOR swizzle, r19 pattern) ----
  for (int idx = tid; idx < 384 * 64; idx += 512) {
    const int r = idx >> 6, w = idx & 63;
    n_lds[(r << 6) | (w ^ ((r & 15) << 2))] = N16[idx];
  }
  // ---- W2 -> LDS (r19 verbatim) ----
  for (int idx = tid; idx < 128 * 64; idx += 512) {
    const int r = idx >> 6, w = idx & 63;
    w2_lds[(r << 6) | (w ^ ((r & 15) << 2))] =
        pack_h2(W2[(size_t)r * 128 + 2 * w], W2[(size_t)r * 128 + 2 * w + 1]);
  }
  if (tid == 0) {
    float s1 = 0.f, s0 = 0.f;
    for (int i = 0; i < 128; ++i) { s1 += lng[i] * Whd[i]; s0 += lnb[i] * Whd[i]; }
    cc_lds[0] = s1; cc_lds[1] = s0 + bhp[0];
  }
  // ---- chunk 0 ----
  {
    const int sl = tid >> 5, part = tid & 31;
    const float2 a = *(const float2*)(x + ((size_t)b * Ll + sl) * 64 + part * 2);
    x16[0][sl * 32 + part] = pack_h2(a.x, a.y);
    if (tid < CH) dt_ch[0][tid] = dtp[(size_t)b * Ll + tid];
    else if (tid < 2 * CH) m_ch[0][tid - CH] = mask[(size_t)b * Ll + (tid - CH)];
  }
  // ---- register-stationary (88 u32): W1, M, Whh(x3), Wx ----
  unsigned w1h[16], mh[16], whr[16], whz[16], whn[16], wxh[8];
#pragma unroll
  for (int ii = 0; ii < 8; ++ii) {
    float4 a4;
    a4 = *(const float4*)&W1[(size_t)j * 128 + (ks << 5) + 4 * ii];
    w1h[2*ii] = pack_h2(a4.x, a4.y); w1h[2*ii+1] = pack_h2(a4.z, a4.w);
    a4 = *(const float4*)&Mf[(size_t)j * 128 + (ks << 5) + 4 * ii];
    mh[2*ii] = pack_h2(a4.x, a4.y); mh[2*ii+1] = pack_h2(a4.z, a4.w);
    a4 = *(const float4*)&Whh[(size_t)j * 128 + (ks << 5) + 4 * ii];
    whr[2*ii] = pack_h2(a4.x, a4.y); whr[2*ii+1] = pack_h2(a4.z, a4.w);
    a4 = *(const float4*)&Whh[(size_t)(128 + j) * 128 + (ks << 5) + 4 * ii];
    whz[2*ii] = pack_h2(a4.x, a4.y); whz[2*ii+1] = pack_h2(a4.z, a4.w);
    a4 = *(const float4*)&Whh[(size_t)(256 + j) * 128 + (ks << 5) + 4 * ii];
    whn[2*ii] = pack_h2(a4.x, a4.y); whn[2*ii+1] = pack_h2(a4.z, a4.w);
  }
#pragma unroll
  for (int ii = 0; ii < 4; ++ii) {
    const float4 a4 = *(const float4*)&Wx[(size_t)j * 64 + (ks << 4) + 4 * ii];
    wxh[2*ii] = pack_h2(a4.x, a4.y); wxh[2*ii+1] = pack_h2(a4.z, a4.w);
  }
  const float bxj = bx[j], b1j = b1[j], b2j = b2[j], cj = cf[j];
  const float bir = bih[j], biz = bih[128 + j], bin_ = bih[256 + j];
  const float bhr = bhh[j], bhz = bhh[128 + j], bhn = bhh[256 + j];
  const float ddr = df[j], ddz = df[128 + j], ddn = df[256 + j];
  const float gw = lng[j] * Whd[j];

  if (tid < 64) { h16[0][tid] = 0u; h16[1][tid] = 0u; }
  float hreg = 0.f;
  float accb = 0.f, cntb = 0.f;
  int mreg = 0;
  float2 rx0 = {0, 0}; float rdt = 0.f; int rmk = 0;
  __syncthreads();

#pragma unroll 1
  for (int t = 0; t < Ll; ++t) {
    const int cb = (t >> 4) & 1, tc = t & 15;

    // =============== chunk-prep (every 16 steps) ===============
    if (tc == 0) {
      // CP1: xe for the 16 steps of this chunk
#pragma unroll 1
      for (int tp = 0; tp < CH; ++tp) {
        float p0 = 0.f, p1 = 0.f;
#pragma unroll
        for (int c = 0; c < 2; ++c) {
          const uint4 xv = *(const uint4*)&x16[cb][tp * 32 + q0x + 4 * c];
          p0 = dot2(wxh[4*c+0], xv.x, p0); p1 = dot2(wxh[4*c+1], xv.y, p1);
          p0 = dot2(wxh[4*c+2], xv.z, p0); p1 = dot2(wxh[4*c+3], xv.w, p1);
        }
        const float xev = fmaxf(qsum(p0, p1) + bxj, 0.f);
        if (ks == 0) ((_Float16*)xech)[tp * 128 + j] = (_Float16)xev;
      }
      __syncthreads();
      // CP2: gi = Wih·xe + bih, one gate at a time (Wih16 streamed from L2)
#pragma unroll 1
      for (int g = 0; g < 3; ++g) {
        unsigned wihs[16];
        const uint4* wp = (const uint4*)(W16 + ((size_t)(g * 128 + j) << 6) + (ks << 4));
#pragma unroll
        for (int i = 0; i < 4; ++i) *(uint4*)&wihs[4 * i] = wp[i];
        const float bg = (g == 0) ? bir : (g == 1) ? biz : bin_;
#pragma unroll 1
        for (int tp = 0; tp < CH; ++tp) {
          const float gv = mv16(wihs, &xech[tp * 64], q0);
          if (ks == 0) gich[(g * CH + tp) * 128 + j] = (_Float16)(gv + bg);
        }
      }
      __syncthreads();
    }

    const float sv = dt_ch[cb][tc] * (float)m_ch[cb][tc] * 0.25f;
    const unsigned* hb = h16[t & 1];
    const int refill = (tc == 8) && ((t >> 4) < 63);

    float v, usum, whr0, whz0, whn0;

    // ===== P1: v = W1·h0 ; Whh_r·h0 ; u0 ; logit(t-1) ; refill-issue =====
    {
      if (refill) {
        const int sl = tid >> 5, part = tid & 31;
        rx0 = *(const float2*)(x + ((size_t)b * Ll + ((t >> 4) + 1) * CH + sl) * 64 + part * 2);
        if (tid < CH) rdt = dtp[(size_t)b * Ll + ((t >> 4) + 1) * CH + tid];
        else if (tid < 2 * CH) rmk = mask[(size_t)b * Ll + ((t >> 4) + 1) * CH + (tid - CH)];
      }
      mv16x2(w1h, whr, hb, q0, v, whr0);
      const float u0 = fast_tanh(v + b1j);
      usum = u0;
      if (ks == 0) ((_Float16*)ubuf[0])[j] = (_Float16)u0;
      if (tid == 0 && t > 0) {
        float S1 = 0.f, S2 = 0.f, SD = 0.f;
#pragma unroll
        for (int q = 0; q < 16; ++q) {
          S1 += red_lds[q * 3 + 0]; S2 += red_lds[q * 3 + 1]; SD += red_lds[q * 3 + 2];
        }
        if (mreg) {
          const float mu = S1 * (1.0f / 128.0f);
          const float var = S2 * (1.0f / 128.0f) - mu * mu;
          const float rstd = rsqrtf(var + 1e-5f);
          accb += rstd * (SD - mu * cc_lds[0]) + cc_lds[1];
          cntb += 1.f;
        }
      }
    }
    __syncthreads();                       // B1

    // ===== P2: v += sv(M·u0+c) ; u1 ; Whh_z·h0 =====
    {
      const float t2 = mv16(mh, ubuf[0], q0);
      whz0 = mv16(whz, hb, q0);
      v = fmaf(sv, t2 + cj, v);
      const float u1 = fast_tanh(v + b1j);
      usum += u1;
      if (ks == 0) ((_Float16*)ubuf[1])[j] = (_Float16)u1;
    }
    __syncthreads();                       // B2

    // ===== P3: v += sv(M·u1+c) ; u2 ; Whh_n·h0 =====
    {
      const float t2 = mv16(mh, ubuf[1], q0);
      whn0 = mv16(whn, hb, q0);
      v = fmaf(sv, t2 + cj, v);
      const float u2 = fast_tanh(v + b1j);
      usum += u2;
      if (ks == 0) ((_Float16*)ubuf[0])[j] = (_Float16)u2;
    }
    __syncthreads();                       // B3

    // ===== P4: v += sv(M·u2+c) ; u3 ; usum =====
    {
      const float t2 = mv16(mh, ubuf[0], q0);
      v = fmaf(sv, t2 + cj, v);
      const float u3 = fast_tanh(v + b1j);
      usum += u3;
      if (ks == 0) ((_Float16*)usumb)[j] = (_Float16)usum;
    }
    __syncthreads();                       // B4

    // ===== P5: {W2,N_r,N_z,N_n}·usum ; gates in-register ; h_new ; LN ; refill-write =====
    {
      float k2a = 0.f, k2b = 0.f, kra = 0.f, krb = 0.f;
      float kza = 0.f, kzb = 0.f, kna = 0.f, knb = 0.f;
      const unsigned* w2r = &w2_lds[j << 6];
      const unsigned* nrr = &n_lds[j << 6];
      const unsigned* nzr = &n_lds[(128 + j) << 6];
      const unsigned* nnr = &n_lds[(256 + j) << 6];
#pragma unroll
      for (int c = 0; c < 4; ++c) {
        const int off = (q0 + 4 * c) ^ swi;
        const uint4 uv = *(const uint4*)&usumb[q0 + 4 * c];
        const uint4 wa = *(const uint4*)&w2r[off];
        k2a = dot2(wa.x, uv.x, k2a); k2b = dot2(wa.y, uv.y, k2b);
        k2a = dot2(wa.z, uv.z, k2a); k2b = dot2(wa.w, uv.w, k2b);
        const uint4 wb = *(const uint4*)&nrr[off];
        kra = dot2(wb.x, uv.x, kra); krb = dot2(wb.y, uv.y, krb);
        kra = dot2(wb.z, uv.z, kra); krb = dot2(wb.w, uv.w, krb);
        const uint4 wc = *(const uint4*)&nzr[off];
        kza = dot2(wc.x, uv.x, kza); kzb = dot2(wc.y, uv.y, kzb);
        kza = dot2(wc.z, uv.z, kza); kzb = dot2(wc.w, uv.w, kzb);
        const uint4 wd = *(const uint4*)&nnr[off];
        kna = dot2(wd.x, uv.x, kna); knb = dot2(wd.y, uv.y, knb);
        kna = dot2(wd.z, uv.z, kna); knb = dot2(wd.w, uv.w, knb);
      }
      const float k2 = qsum(k2a, k2b);
      const float kr = qsum(kra, krb);
      const float kz = qsum(kza, kzb);
      const float kn = qsum(kna, knb);
      const float sv4 = 4.f * sv;
      const float hf = hreg + sv * k2 + sv4 * b2j;
      const float prer = whr0 + sv * kr + sv4 * ddr + bhr;
      const float prez = whz0 + sv * kz + sv4 * ddz + bhz;
      const float pren = whn0 + sv * kn + sv4 * ddn + bhn;
      const float gir = (float)gich[(0 * CH + tc) * 128 + j];
      const float giz = (float)gich[(1 * CH + tc) * 128 + j];
      const float gin = (float)gich[(2 * CH + tc) * 128 + j];
      const float rr = fast_sigmoid(gir + prer);
      const float zz = fast_sigmoid(giz + prez);
      const float gn_ = fast_tanh(gin + rr * pren);
      const float hg = (1.f - zz) * gn_ + zz * hf;
      const int actv = (actb[t >> 5] >> (t & 31)) & 1;
      hreg = actv ? hg : hf;
      if (ks == 0) ((_Float16*)h16[(t + 1) & 1])[j] = (_Float16)hreg;
      float s1 = hreg, s2 = hreg * hreg, sd = hreg * gw;
#pragma unroll
      for (int o = 4; o <= 16; o <<= 1) {
        s1 += __shfl_xor(s1, o); s2 += __shfl_xor(s2, o); sd += __shfl_xor(sd, o);
      }
      if ((lane & 31) == 0) {
        const int slot = (wv << 1) | (lane >> 5);
        red_lds[slot * 3 + 0] = s1; red_lds[slot * 3 + 1] = s2; red_lds[slot * 3 + 2] = sd;
      }
      if (tid == 0) mreg = m_ch[cb][tc];
      if (refill) {
        const int nb = ((t >> 4) + 1) & 1;
        const int sl = tid >> 5, part = tid & 31;
        x16[nb][sl * 32 + part] = pack_h2(rx0.x, rx0.y);
        if (tid < CH) dt_ch[nb][tid] = rdt;
        else if (tid < 2 * CH) m_ch[nb][tid - CH] = rmk;
      }
    }
    __syncthreads();                       // B5
  }

  // ---- epilogue: logit for t=1023 ----
  if (tid == 0) {
    float S1 = 0.f, S2 = 0.f, SD = 0.f;
#pragma unroll
    for (int q = 0; q < 16; ++q) {
      S1 += red_lds[q * 3 + 0]; S2 += red_lds[q * 3 + 1]; SD += red_lds[q * 3 + 2];
    }
    if (mreg) {
      const float mu = S1 * (1.0f / 128.0f);
      const float var = S2 * (1.0f / 128.0f) - mu * mu;
      const float rstd = rsqrtf(var + 1e-5f);
      accb += rstd * (SD - mu * cc_lds[0]) + cc_lds[1];
      cntb += 1.f;
    }
    out[b] = accb / fmaxf(cntb, 1.f);
  }
}

// ---------------- host ----------------
extern "C" void kernel_launch(void* const* d_in, const int* in_sizes, int n_in,
                              void* d_out, int out_size, void* d_ws, size_t ws_size,
                              hipStream_t stream) {
  const float* x    = (const float*)d_in[0];
  const float* dt   = (const float*)d_in[1];
  const int*   mask = (const int*)d_in[2];
  const float* Wx   = (const float*)d_in[3];
  const float* bx   = (const float*)d_in[4];
  const float* W1   = (const float*)d_in[5];
  const float* b1   = (const float*)d_in[6];
  const float* W2   = (const float*)d_in[7];
  const float* b2   = (const float*)d_in[8];
  const float* Wih  = (const float*)d_in[9];
  const float* bih  = (const float*)d_in[10];
  const float* Whh  = (const float*)d_in[11];
  const float* bhh  = (const float*)d_in[12];
  const float* lng  = (const float*)d_in[13];
  const float* lnb  = (const float*)d_in[14];
  const float* Wh   = (const float*)d_in[15];
  const float* bh   = (const float*)d_in[16];
  float* ws = (float*)d_ws;   // needs 66048 words = 258 KB (r17-proven)
  float* out = (float*)d_out;

  k_prep<<<dim3(258), dim3(256), 0, stream>>>(W1, W2, Whh, Wih, b2, ws);
  k_fused<<<dim3(Bb), dim3(512), 0, stream>>>(
      x, dt, mask, Wx, bx, W1, b1, W2, b2, Wih, bih, Whh, bhh,
      lng, lnb, Wh, bh, ws, out);
}